// Round 2
// baseline (214.128 us; speedup 1.0000x reference)
//
#include <hip/hip_runtime.h>

using sh8 = __attribute__((ext_vector_type(8))) short;
using sh4 = __attribute__((ext_vector_type(4))) short;
using fx4 = __attribute__((ext_vector_type(4))) float;

#define MFMA(a,b,c)   __builtin_amdgcn_mfma_f32_16x16x32_bf16((a),(b),(c),0,0,0)

// RNE cast (epilogue scalars — accuracy-critical path)
__device__ __forceinline__ short f2bf(float f) {
    union { float f; unsigned u; } v; v.f = f;
    return (short)((v.u + 0x7fffu + ((v.u >> 16) & 1u)) >> 16);
}

// Round-half-up pack of two floats to a bf16 pair (3 VALU: 2 add + 1 perm).
__device__ __forceinline__ unsigned bfpair(float lo, float hi) {
    unsigned ul = __float_as_uint(lo) + 0x8000u;
    unsigned uh = __float_as_uint(hi) + 0x8000u;
    return __builtin_amdgcn_perm(uh, ul, 0x07060302);  // [hi.bf16 : lo.bf16]
}

__device__ __forceinline__ sh8 pack8(float4 a, float4 b) {
    union { unsigned u[4]; sh8 s; } r;
    r.u[0] = bfpair(a.x, a.y);
    r.u[1] = bfpair(a.z, a.w);
    r.u[2] = bfpair(b.x, b.y);
    r.u[3] = bfpair(b.z, b.w);
    return r.s;
}

// q scale: D^-0.5 * log2(e) folded together; attn uses exp2 directly.
#define QSCALE 0.18033688011112042f

// DMA one 1KB chunk: per-lane global src, wave-uniform LDS dst (+lane*16 by HW)
#define GLOAD_LDS16(gsrc, ldst) __builtin_amdgcn_global_load_lds( \
    (const __attribute__((address_space(1))) void*)(gsrc),        \
    (__attribute__((address_space(3))) void*)(ldst), 16, 0, 0)

// ===========================================================================
// Fragment layouts (written by prep_k, consumed by attn_k):
//   k_ws : per bh, 256 chunks of 512 shorts. chunk fo = (kb*4+nt)*2+half
//          holds K[key=kb*64+nt*16+llo][d=half*32+lhi*8+j] at lane=lhi*16+llo,
//          slot j.  Group (kb,g) -> 4 consecutive chunks at fo = (kb*2+g)*4.
//   vT_ws: per bh, 256 chunks of 512 shorts. chunk vo = (kb*2+g)*4+dt holds
//          V[key=kb*64+g*32+(i>>2)*16+lhi*4+(i&3)][d=dt*16+llo] at
//          lane=lhi*16+llo, slot i.  (i.e. the K=32 MFMA B-operand
//          permutation matching the P fragment built from two S^T tiles.)
//   Chunks are lane-linear (lane*16B) => global_load_lds-compatible.
// ===========================================================================

// prep_k: merged qgemm (blocks 0..383) + kvgemm (384..511) + depth_k cast
// (512..1535) + depth_v fragment gather (1536..2047).
__global__ __launch_bounds__(256) void prep_k(const float* __restrict__ x,
                                              const float* __restrict__ Wq,
                                              const float* __restrict__ bq,
                                              const float* __restrict__ Wkv,
                                              const float* __restrict__ bkv,
                                              const float* __restrict__ dk,
                                              const float* __restrict__ dv,
                                              float* __restrict__ ok,
                                              float* __restrict__ ov,
                                              short* __restrict__ q_ws,
                                              short* __restrict__ k_ws,
                                              short* __restrict__ vT_ws)
{
    __shared__ alignas(16) short Al[128 * 40];
    __shared__ alignas(16) short Bl[128 * 40];
    const int blk = blockIdx.x;
    const int t   = threadIdx.x;

    if (blk < 512) {
        // ----- 128x128-tile bf16 GEMM path (qgemm or kvgemm) -----
        const bool isq = (blk < 384);
        const int  i   = isq ? blk : blk - 384;
        const int  nbx = isq ? 6 : 2;
        const int  bm  = (i / nbx) * 128, bn = (i % nbx) * 128;
        const float* Wmat = isq ? Wq : Wkv;

        const int wave = t >> 6, lane = t & 63;
        const int wm   = wave >> 1, wn = wave & 1;
        const int lhi  = lane >> 4, llo = lane & 15;

        const int srow = t >> 1, scol = (t & 1) * 16;
        const float* ap = x    + (size_t)(bm + srow) * 768 + scol;
        const float* bp = Wmat + (size_t)(bn + srow) * 768 + scol;

        fx4 zero = {0.f, 0.f, 0.f, 0.f};
        fx4 acc[4][4];
        #pragma unroll
        for (int a = 0; a < 4; ++a)
            #pragma unroll
            for (int b2 = 0; b2 < 4; ++b2) acc[a][b2] = zero;

        float4 pa0 = *(const float4*)(ap);     float4 pa1 = *(const float4*)(ap + 4);
        float4 pa2 = *(const float4*)(ap + 8); float4 pa3 = *(const float4*)(ap + 12);
        float4 pb0 = *(const float4*)(bp);     float4 pb1 = *(const float4*)(bp + 4);
        float4 pb2 = *(const float4*)(bp + 8); float4 pb3 = *(const float4*)(bp + 12);

        for (int k0 = 0; k0 < 768; k0 += 32) {
            __syncthreads();
            *(sh8*)&Al[srow*40 + scol]     = pack8(pa0, pa1);
            *(sh8*)&Al[srow*40 + scol + 8] = pack8(pa2, pa3);
            *(sh8*)&Bl[srow*40 + scol]     = pack8(pb0, pb1);
            *(sh8*)&Bl[srow*40 + scol + 8] = pack8(pb2, pb3);
            __syncthreads();
            if (k0 + 32 < 768) {
                pa0 = *(const float4*)(ap + k0+32);  pa1 = *(const float4*)(ap + k0+36);
                pa2 = *(const float4*)(ap + k0+40);  pa3 = *(const float4*)(ap + k0+44);
                pb0 = *(const float4*)(bp + k0+32);  pb1 = *(const float4*)(bp + k0+36);
                pb2 = *(const float4*)(bp + k0+40);  pb3 = *(const float4*)(bp + k0+44);
            }
            sh8 af[4], bf[4];
            #pragma unroll
            for (int mt = 0; mt < 4; ++mt)
                af[mt] = *(const sh8*)&Al[(wm*64 + mt*16 + llo)*40 + lhi*8];
            #pragma unroll
            for (int nt = 0; nt < 4; ++nt)
                bf[nt] = *(const sh8*)&Bl[(wn*64 + nt*16 + llo)*40 + lhi*8];
            #pragma unroll
            for (int mt = 0; mt < 4; ++mt)
                #pragma unroll
                for (int nt = 0; nt < 4; ++nt)
                    acc[mt][nt] = MFMA(af[mt], bf[nt], acc[mt][nt]);
        }

        if (isq) {
            #pragma unroll
            for (int nt = 0; nt < 4; ++nt) {
                const int c = bn + wn*64 + nt*16 + llo;
                const float bias = bq[c];
                const int g = c >> 7, h = (c >> 6) & 1, d = c & 63;
                #pragma unroll
                for (int mt = 0; mt < 4; ++mt) {
                    const int m0 = bm + wm*64 + mt*16 + lhi*4;
                    #pragma unroll
                    for (int r = 0; r < 4; ++r) {
                        const int m = m0 + r;
                        const int b = m >> 10, n = m & 1023;
                        const float val = (acc[mt][nt][r] + bias) * QSCALE;
                        q_ws[((size_t)(b*2 + h)*6144 + n*6 + g)*64 + d] = f2bf(val);
                    }
                }
            }
        } else {
            #pragma unroll
            for (int nt = 0; nt < 4; ++nt) {
                const int c = bn + wn*64 + nt*16 + llo;     // 0..255
                const float bias = bkv[c];
                const int s = c >> 7, h = (c >> 6) & 1, d = c & 63;
                #pragma unroll
                for (int mt = 0; mt < 4; ++mt) {
                    const int m0 = bm + wm*64 + mt*16 + lhi*4;
                    const int b = m0 >> 10, n0 = m0 & 1023;
                    float vals[4];
                    #pragma unroll
                    for (int r = 0; r < 4; ++r) vals[r] = acc[mt][nt][r] + bias;
                    const int key = 1024 + n0;              // n0 % 4 == 0
                    if (s == 0) {
                        #pragma unroll
                        for (int r = 0; r < 4; ++r)
                            ok[((size_t)(b*1024 + n0 + r)*2 + h)*64 + d] = vals[r];
                        const int kb_ = key >> 6, nt_ = (key >> 4) & 3;
                        const int half = d >> 5, lhiK = (d >> 3) & 3, j = d & 7;
                        const size_t base = (size_t)(b*2 + h)*131072
                            + (size_t)(((((kb_*4 + nt_)*2 + half)*64) + lhiK*16 + (key & 15))*8 + j);
                        #pragma unroll
                        for (int r = 0; r < 4; ++r)
                            k_ws[base + r*8] = f2bf(vals[r]);
                    } else {
                        #pragma unroll
                        for (int r = 0; r < 4; ++r)
                            ov[((size_t)(b*1024 + n0 + r)*2 + h)*64 + d] = vals[r];
                        const int kb_ = key >> 6, g_ = (key >> 5) & 1, k5 = key & 31;
                        const int half5 = k5 >> 4, lhi5 = (k5 >> 2) & 3;   // j5 = r
                        const int dt_ = d >> 4, llov = d & 15;
                        short4 pk = make_short4(f2bf(vals[0]), f2bf(vals[1]),
                                                f2bf(vals[2]), f2bf(vals[3]));
                        const size_t base = (size_t)(b*2 + h)*131072
                            + (size_t)(((((kb_*2 + g_)*4 + dt_)*64) + lhi5*16 + llov)*8 + half5*4);
                        *(short4*)&vT_ws[base] = pk;
                    }
                }
            }
        }
    } else if (blk < 1536) {
        // ----- depth_k cast: [b][tt][h][d] fp32 -> k_ws fragment layout -----
        const size_t idx4 = ((size_t)(blk - 512) * 256 + t) * 4;
        const int b  = (int)(idx4 >> 17);
        const int rm = (int)(idx4 & 131071);
        const int tt = rm >> 7, h = (rm >> 6) & 1, d = rm & 63;   // d % 4 == 0
        float4 v = *(const float4*)(dk + idx4);
        short4 pk = make_short4(f2bf(v.x), f2bf(v.y), f2bf(v.z), f2bf(v.w));
        const int kb_ = tt >> 6, nt_ = (tt >> 4) & 3, lloK = tt & 15;
        const int half = d >> 5, lhiK = (d >> 3) & 3, j = d & 7;  // j in {0,4}
        const size_t addr = (size_t)(b*2 + h)*131072
            + (size_t)(((((kb_*4 + nt_)*2 + half)*64) + lhiK*16 + lloK)*8 + j);
        *(short4*)&k_ws[addr] = pk;
    } else {
        // ----- depth_v: direct gather into V fragment layout -----
        const int unit = (blk - 1536)*4 + (t >> 6);   // 0..2047
        const int lane = t & 63, lhi = lane >> 4, llo = lane & 15;
        const int dt_ = unit & 3, g_ = (unit >> 2) & 1;
        const int kb_ = (unit >> 3) & 15, bh = unit >> 7;
        const int b = bh >> 1, h = bh & 1;
        const float* s0 = dv
            + ((size_t)((b*1024 + kb_*64 + g_*32 + lhi*4)*2 + h))*64 + dt_*16 + llo;
        union { short s[8]; sh8 v8; } o;
        #pragma unroll
        for (int jj = 0; jj < 4; ++jj) o.s[jj]     = f2bf(s0[(size_t)jj * 128]);
        #pragma unroll
        for (int jj = 0; jj < 4; ++jj) o.s[4 + jj] = f2bf(s0[(size_t)(16 + jj) * 128]);
        *(sh8*)&vT_ws[((size_t)bh*256 + (kb_*2 + g_)*4 + dt_)*512 + lane*8] = o.v8;
    }
}

// ---------------------------------------------------------------------------
// Attention v7: LDS-pipelined.  K/V chunks are DMA'd global->LDS with
// global_load_lds (no VGPR round-trip, no VALU), 4-deep ring buffer, issued
// 2 groups ahead with counted s_waitcnt vmcnt(4) + raw s_barrier (loads stay
// in flight across barriers).  4 waves share each fetch => L2 traffic /4.
// Compute per group unchanged: S^T MFMA pair -> exp2 -> bfpair pack ->
// full-rate PV MFMA + ones-MFMA row sums.
// ---------------------------------------------------------------------------
__global__ __launch_bounds__(256) void attn_k(const short* __restrict__ q_ws,
                                              const short* __restrict__ k_ws,
                                              const short* __restrict__ vT_ws,
                                              short* __restrict__ o_ws)
{
    __shared__ alignas(16) short L[4][8][512];   // ring buf: 4 x (4 K + 4 V chunks)
    const int t    = threadIdx.x;
    const int wave = t >> 6, lane = t & 63;
    const int lhi  = lane >> 4, llo = lane & 15;
    const int bh   = blockIdx.y;
    const int b    = bh >> 1, h = bh & 1;
    const int qt   = blockIdx.x;               // 192-q tile index

    const short* qb = q_ws + ((size_t)bh*6144 + qt*192 + wave*48) * 64;
    sh8 qf[3][2];
    #pragma unroll
    for (int s = 0; s < 3; ++s) {
        qf[s][0] = *(const sh8*)(qb + (s*16 + llo)*64 + lhi*8);
        qf[s][1] = *(const sh8*)(qb + (s*16 + llo)*64 + lhi*8 + 32);
    }

    const short* kbase = k_ws  + (size_t)bh*131072;
    const short* vbase = vT_ws + (size_t)bh*131072;

    fx4 zero = {0.f, 0.f, 0.f, 0.f};
    fx4 oacc[3][4];
    fx4 lacc[3];
    #pragma unroll
    for (int s = 0; s < 3; ++s) {
        lacc[s] = zero;
        #pragma unroll
        for (int dt = 0; dt < 4; ++dt) oacc[s][dt] = zero;
    }

    union { unsigned u[4]; sh8 s8; } onesu;
    onesu.u[0] = onesu.u[1] = onesu.u[2] = onesu.u[3] = 0x3F803F80u;  // bf16 1.0 x8
    const sh8 ones = onesu.s8;

    // wave w DMAs K-chunk w and V-chunk w of group g into ring slot g&3.
    // global chunk = lane-linear 1KB; LDS dst wave-uniform (HW adds lane*16).
    auto stage = [&](int g) {
        const short* ks = kbase + ((size_t)g*4 + wave)*512 + lane*8;
        const short* vs = vbase + ((size_t)g*4 + wave)*512 + lane*8;
        GLOAD_LDS16(ks, &L[g & 3][wave][0]);
        GLOAD_LDS16(vs, &L[g & 3][4 + wave][0]);
    };

    stage(0);
    stage(1);                     // outstanding: 4 DMA ops per wave

    for (int g = 0; g < 64; ++g) {
        if (g < 62) {
            stage(g + 2);         // outstanding 6
            asm volatile("s_waitcnt vmcnt(4)" ::: "memory");   // group g landed
        } else if (g == 62) {
            asm volatile("s_waitcnt vmcnt(2)" ::: "memory");
        } else {
            asm volatile("s_waitcnt vmcnt(0)" ::: "memory");
        }
        __builtin_amdgcn_s_barrier();          // all waves' group-g DMAs visible
        __builtin_amdgcn_sched_barrier(0);     // forbid hoisting ds_reads above

        const short* Lb = (const short*)&L[g & 3][0][0];
        const int lo = lane * 8;
        sh8 K0 = *(const sh8*)(Lb + lo);
        sh8 K1 = *(const sh8*)(Lb + 512  + lo);
        sh8 K2 = *(const sh8*)(Lb + 1024 + lo);
        sh8 K3 = *(const sh8*)(Lb + 1536 + lo);
        sh8 V0 = *(const sh8*)(Lb + 2048 + lo);
        sh8 V1 = *(const sh8*)(Lb + 2560 + lo);
        sh8 V2 = *(const sh8*)(Lb + 3072 + lo);
        sh8 V3 = *(const sh8*)(Lb + 3584 + lo);

        #pragma unroll
        for (int s = 0; s < 3; ++s) {
            fx4 stA = MFMA(K0, qf[s][0], zero); stA = MFMA(K1, qf[s][1], stA);
            fx4 stB = MFMA(K2, qf[s][0], zero); stB = MFMA(K3, qf[s][1], stB);
            float pa0 = __builtin_amdgcn_exp2f(stA[0]);
            float pa1 = __builtin_amdgcn_exp2f(stA[1]);
            float pa2 = __builtin_amdgcn_exp2f(stA[2]);
            float pa3 = __builtin_amdgcn_exp2f(stA[3]);
            float pb0 = __builtin_amdgcn_exp2f(stB[0]);
            float pb1 = __builtin_amdgcn_exp2f(stB[1]);
            float pb2 = __builtin_amdgcn_exp2f(stB[2]);
            float pb3 = __builtin_amdgcn_exp2f(stB[3]);
            union { unsigned u[4]; sh8 s8; } pu;
            pu.u[0] = bfpair(pa0, pa1);
            pu.u[1] = bfpair(pa2, pa3);
            pu.u[2] = bfpair(pb0, pb1);
            pu.u[3] = bfpair(pb2, pb3);
            lacc[s]    = MFMA(pu.s8, ones, lacc[s]);
            oacc[s][0] = MFMA(pu.s8, V0, oacc[s][0]);
            oacc[s][1] = MFMA(pu.s8, V1, oacc[s][1]);
            oacc[s][2] = MFMA(pu.s8, V2, oacc[s][2]);
            oacc[s][3] = MFMA(pu.s8, V3, oacc[s][3]);
        }
    }

    // epilogue: lacc[s][r] already holds the full denominator for q-row
    // s*16 + lhi*4 + r (identical across llo) — no shuffles needed.
    #pragma unroll
    for (int s = 0; s < 3; ++s) {
        #pragma unroll
        for (int r = 0; r < 4; ++r) {
            const float iq = 1.0f / lacc[s][r];
            const int qi = qt*192 + wave*48 + s*16 + lhi*4 + r;
            const int n = qi / 6, g = qi % 6;
            short* orow = o_ws + ((size_t)(b*1024 + n))*768 + g*128 + h*64;
            #pragma unroll
            for (int dt = 0; dt < 4; ++dt)
                orow[dt*16 + llo] = f2bf(oacc[s][dt][r] * iq);
        }
    }
}

// ---------------------------------------------------------------------------
// proj GEMM: out = o(8192x768,bf16) @ Wproj^T + bproj -> fp32.  grid (6, 64).
// ---------------------------------------------------------------------------
__global__ __launch_bounds__(256) void projgemm_k(const short* __restrict__ o_ws,
                                                  const float* __restrict__ Wp,
                                                  const float* __restrict__ bpj,
                                                  float* __restrict__ out)
{
    __shared__ alignas(16) short Al[128 * 40];
    __shared__ alignas(16) short Bl[128 * 40];
    const int t    = threadIdx.x;
    const int wave = t >> 6, lane = t & 63;
    const int wm   = wave >> 1, wn = wave & 1;
    const int lhi  = lane >> 4, llo = lane & 15;
    const int bm   = blockIdx.y * 128, bn = blockIdx.x * 128;

    const int srow = t >> 1, scol = (t & 1) * 16;
    const short* ap = o_ws + (size_t)(bm + srow) * 768 + scol;
    const float* bp = Wp   + (size_t)(bn + srow) * 768 + scol;

    fx4 zero = {0.f, 0.f, 0.f, 0.f};
    fx4 acc[4][4];
    #pragma unroll
    for (int i = 0; i < 4; ++i)
        #pragma unroll
        for (int j = 0; j < 4; ++j) acc[i][j] = zero;

    sh8 qa0 = *(const sh8*)(ap), qa1 = *(const sh8*)(ap + 8);
    float4 pb0 = *(const float4*)(bp);     float4 pb1 = *(const float4*)(bp + 4);
    float4 pb2 = *(const float4*)(bp + 8); float4 pb3 = *(const float4*)(bp + 12);

    for (int k0 = 0; k0 < 768; k0 += 32) {
        __syncthreads();
        *(sh8*)&Al[srow*40 + scol]     = qa0;
        *(sh8*)&Al[srow*40 + scol + 8] = qa1;
        *(sh8*)&Bl[srow*40 + scol]     = pack8(pb0, pb1);
        *(sh8*)&Bl[srow*40 + scol + 8] = pack8(pb2, pb3);
        __syncthreads();
        if (k0 + 32 < 768) {
            qa0 = *(const sh8*)(ap + k0+32);  qa1 = *(const sh8*)(ap + k0+40);
            pb0 = *(const float4*)(bp + k0+32);  pb1 = *(const float4*)(bp + k0+36);
            pb2 = *(const float4*)(bp + k0+40);  pb3 = *(const float4*)(bp + k0+44);
        }
        sh8 af[4], bf[4];
        #pragma unroll
        for (int mt = 0; mt < 4; ++mt)
            af[mt] = *(const sh8*)&Al[(wm*64 + mt*16 + llo)*40 + lhi*8];
        #pragma unroll
        for (int nt = 0; nt < 4; ++nt)
            bf[nt] = *(const sh8*)&Bl[(wn*64 + nt*16 + llo)*40 + lhi*8];
        #pragma unroll
        for (int mt = 0; mt < 4; ++mt)
            #pragma unroll
            for (int nt = 0; nt < 4; ++nt)
                acc[mt][nt] = MFMA(af[mt], bf[nt], acc[mt][nt]);
    }

    #pragma unroll
    for (int nt = 0; nt < 4; ++nt) {
        const int c = bn + wn*64 + nt*16 + llo;
        const float bias = bpj[c];
        #pragma unroll
        for (int mt = 0; mt < 4; ++mt) {
            const int m0 = bm + wm*64 + mt*16 + lhi*4;
            #pragma unroll
            for (int r = 0; r < 4; ++r)
                out[(size_t)(m0 + r)*768 + c] = acc[mt][nt][r] + bias;
        }
    }
}

// ---------------------------------------------------------------------------
extern "C" void kernel_launch(void* const* d_in, const int* in_sizes, int n_in,
                              void* d_out, int out_size, void* d_ws, size_t ws_size,
                              hipStream_t stream)
{
    const float* x   = (const float*)d_in[0];
    const float* dk  = (const float*)d_in[1];
    const float* dv  = (const float*)d_in[2];
    const float* Wq  = (const float*)d_in[3];
    const float* bq  = (const float*)d_in[4];
    const float* Wkv = (const float*)d_in[5];
    const float* bkv = (const float*)d_in[6];
    const float* Wp  = (const float*)d_in[7];
    const float* bpj = (const float*)d_in[8];

    float* out = (float*)d_out;
    float* ok  = out + 6291456;            // k output (8,1024,2,64)
    float* ov  = out + 7340032;            // v output

    char* ws = (char*)d_ws;
    short* q_ws  = (short*)(ws);                    // 12,582,912 B
    short* k_ws  = (short*)(ws + 12582912);         //  4,194,304 B (frag layout)
    short* vT_ws = (short*)(ws + 16777216);         //  4,194,304 B (frag layout)
    short* o_ws  = (short*)(ws + 20971520);         // 12,582,912 B  (32 MiB total)

    prep_k     <<<dim3(2048),   256, 0, stream>>>(x, Wq, bq, Wkv, bkv, dk, dv,
                                                  ok, ov, q_ws, k_ws, vT_ws);
    attn_k     <<<dim3(32, 16), 256, 0, stream>>>(q_ws, k_ws, vT_ws, o_ws);
    projgemm_k <<<dim3(6, 64),  256, 0, stream>>>(o_ws, Wp, bpj, out);
}

// Round 3
// 209.618 us; speedup vs baseline: 1.0215x; 1.0215x over previous
//
#include <hip/hip_runtime.h>

using sh8 = __attribute__((ext_vector_type(8))) short;
using sh4 = __attribute__((ext_vector_type(4))) short;
using fx4 = __attribute__((ext_vector_type(4))) float;

#define MFMA(a,b,c)   __builtin_amdgcn_mfma_f32_16x16x32_bf16((a),(b),(c),0,0,0)

// RNE cast (epilogue scalars — accuracy-critical path)
__device__ __forceinline__ short f2bf(float f) {
    union { float f; unsigned u; } v; v.f = f;
    return (short)((v.u + 0x7fffu + ((v.u >> 16) & 1u)) >> 16);
}

// Single-instruction RNE pack of two floats to a bf16 pair (lo in low half).
__device__ __forceinline__ unsigned cvtpk(float lo, float hi) {
    unsigned r;
    asm("v_cvt_pk_bf16_f32 %0, %1, %2" : "=v"(r) : "v"(lo), "v"(hi));
    return r;
}

__device__ __forceinline__ sh8 pack8(float4 a, float4 b) {
    union { unsigned u[4]; sh8 s; } r;
    r.u[0] = cvtpk(a.x, a.y);
    r.u[1] = cvtpk(a.z, a.w);
    r.u[2] = cvtpk(b.x, b.y);
    r.u[3] = cvtpk(b.z, b.w);
    return r.s;
}

// q scale: D^-0.5 * log2(e) folded together; attn uses exp2 directly.
#define QSCALE 0.18033688011112042f

// DMA one 1KB chunk: per-lane global src, wave-uniform LDS dst (+lane*16 by HW)
#define GLOAD_LDS16(gsrc, ldst) __builtin_amdgcn_global_load_lds( \
    (const __attribute__((address_space(1))) void*)(gsrc),        \
    (__attribute__((address_space(3))) void*)(ldst), 16, 0, 0)

// ===========================================================================
// Fragment layouts (written by prep_k, consumed by attn_k):
//   k_ws : per bh, 256 chunks of 512 shorts. chunk fo = (kb*4+nt)*2+half
//          holds K[key=kb*64+nt*16+llo][d=half*32+lhi*8+j] at lane=lhi*16+llo,
//          slot j.  Group (kb,g) -> 4 consecutive chunks at fo = (kb*2+g)*4.
//   vT_ws: per bh, 256 chunks of 512 shorts. chunk vo = (kb*2+g)*4+dt holds
//          V[key=kb*64+g*32+(i>>2)*16+lhi*4+(i&3)][d=dt*16+llo] at
//          lane=lhi*16+llo, slot i.  (i.e. the K=32 MFMA B-operand
//          permutation matching the P fragment built from two S^T tiles.)
//   Chunks are lane-linear (lane*16B) => global_load_lds-compatible.
// ===========================================================================

// prep_k: merged qgemm (blocks 0..383) + kvgemm (384..511) + depth_k cast
// (512..1535) + depth_v fragment gather (1536..2047).
__global__ __launch_bounds__(256) void prep_k(const float* __restrict__ x,
                                              const float* __restrict__ Wq,
                                              const float* __restrict__ bq,
                                              const float* __restrict__ Wkv,
                                              const float* __restrict__ bkv,
                                              const float* __restrict__ dk,
                                              const float* __restrict__ dv,
                                              float* __restrict__ ok,
                                              float* __restrict__ ov,
                                              short* __restrict__ q_ws,
                                              short* __restrict__ k_ws,
                                              short* __restrict__ vT_ws)
{
    __shared__ alignas(16) short Al[128 * 40];
    __shared__ alignas(16) short Bl[128 * 40];
    const int blk = blockIdx.x;
    const int t   = threadIdx.x;

    if (blk < 512) {
        // ----- 128x128-tile bf16 GEMM path (qgemm or kvgemm) -----
        const bool isq = (blk < 384);
        const int  i   = isq ? blk : blk - 384;
        const int  nbx = isq ? 6 : 2;
        const int  bm  = (i / nbx) * 128, bn = (i % nbx) * 128;
        const float* Wmat = isq ? Wq : Wkv;

        const int wave = t >> 6, lane = t & 63;
        const int wm   = wave >> 1, wn = wave & 1;
        const int lhi  = lane >> 4, llo = lane & 15;

        const int srow = t >> 1, scol = (t & 1) * 16;
        const float* ap = x    + (size_t)(bm + srow) * 768 + scol;
        const float* bp = Wmat + (size_t)(bn + srow) * 768 + scol;

        fx4 zero = {0.f, 0.f, 0.f, 0.f};
        fx4 acc[4][4];
        #pragma unroll
        for (int a = 0; a < 4; ++a)
            #pragma unroll
            for (int b2 = 0; b2 < 4; ++b2) acc[a][b2] = zero;

        float4 pa0 = *(const float4*)(ap);     float4 pa1 = *(const float4*)(ap + 4);
        float4 pa2 = *(const float4*)(ap + 8); float4 pa3 = *(const float4*)(ap + 12);
        float4 pb0 = *(const float4*)(bp);     float4 pb1 = *(const float4*)(bp + 4);
        float4 pb2 = *(const float4*)(bp + 8); float4 pb3 = *(const float4*)(bp + 12);

        for (int k0 = 0; k0 < 768; k0 += 32) {
            __syncthreads();
            *(sh8*)&Al[srow*40 + scol]     = pack8(pa0, pa1);
            *(sh8*)&Al[srow*40 + scol + 8] = pack8(pa2, pa3);
            *(sh8*)&Bl[srow*40 + scol]     = pack8(pb0, pb1);
            *(sh8*)&Bl[srow*40 + scol + 8] = pack8(pb2, pb3);
            __syncthreads();
            if (k0 + 32 < 768) {
                pa0 = *(const float4*)(ap + k0+32);  pa1 = *(const float4*)(ap + k0+36);
                pa2 = *(const float4*)(ap + k0+40);  pa3 = *(const float4*)(ap + k0+44);
                pb0 = *(const float4*)(bp + k0+32);  pb1 = *(const float4*)(bp + k0+36);
                pb2 = *(const float4*)(bp + k0+40);  pb3 = *(const float4*)(bp + k0+44);
            }
            sh8 af[4], bf[4];
            #pragma unroll
            for (int mt = 0; mt < 4; ++mt)
                af[mt] = *(const sh8*)&Al[(wm*64 + mt*16 + llo)*40 + lhi*8];
            #pragma unroll
            for (int nt = 0; nt < 4; ++nt)
                bf[nt] = *(const sh8*)&Bl[(wn*64 + nt*16 + llo)*40 + lhi*8];
            #pragma unroll
            for (int mt = 0; mt < 4; ++mt)
                #pragma unroll
                for (int nt = 0; nt < 4; ++nt)
                    acc[mt][nt] = MFMA(af[mt], bf[nt], acc[mt][nt]);
        }

        if (isq) {
            #pragma unroll
            for (int nt = 0; nt < 4; ++nt) {
                const int c = bn + wn*64 + nt*16 + llo;
                const float bias = bq[c];
                const int g = c >> 7, h = (c >> 6) & 1, d = c & 63;
                #pragma unroll
                for (int mt = 0; mt < 4; ++mt) {
                    const int m0 = bm + wm*64 + mt*16 + lhi*4;
                    #pragma unroll
                    for (int r = 0; r < 4; ++r) {
                        const int m = m0 + r;
                        const int b = m >> 10, n = m & 1023;
                        const float val = (acc[mt][nt][r] + bias) * QSCALE;
                        q_ws[((size_t)(b*2 + h)*6144 + n*6 + g)*64 + d] = f2bf(val);
                    }
                }
            }
        } else {
            #pragma unroll
            for (int nt = 0; nt < 4; ++nt) {
                const int c = bn + wn*64 + nt*16 + llo;     // 0..255
                const float bias = bkv[c];
                const int s = c >> 7, h = (c >> 6) & 1, d = c & 63;
                #pragma unroll
                for (int mt = 0; mt < 4; ++mt) {
                    const int m0 = bm + wm*64 + mt*16 + lhi*4;
                    const int b = m0 >> 10, n0 = m0 & 1023;
                    float vals[4];
                    #pragma unroll
                    for (int r = 0; r < 4; ++r) vals[r] = acc[mt][nt][r] + bias;
                    const int key = 1024 + n0;              // n0 % 4 == 0
                    if (s == 0) {
                        #pragma unroll
                        for (int r = 0; r < 4; ++r)
                            ok[((size_t)(b*1024 + n0 + r)*2 + h)*64 + d] = vals[r];
                        const int kb_ = key >> 6, nt_ = (key >> 4) & 3;
                        const int half = d >> 5, lhiK = (d >> 3) & 3, j = d & 7;
                        const size_t base = (size_t)(b*2 + h)*131072
                            + (size_t)(((((kb_*4 + nt_)*2 + half)*64) + lhiK*16 + (key & 15))*8 + j);
                        #pragma unroll
                        for (int r = 0; r < 4; ++r)
                            k_ws[base + r*8] = f2bf(vals[r]);
                    } else {
                        #pragma unroll
                        for (int r = 0; r < 4; ++r)
                            ov[((size_t)(b*1024 + n0 + r)*2 + h)*64 + d] = vals[r];
                        const int kb_ = key >> 6, g_ = (key >> 5) & 1, k5 = key & 31;
                        const int half5 = k5 >> 4, lhi5 = (k5 >> 2) & 3;   // j5 = r
                        const int dt_ = d >> 4, llov = d & 15;
                        short4 pk = make_short4(f2bf(vals[0]), f2bf(vals[1]),
                                                f2bf(vals[2]), f2bf(vals[3]));
                        const size_t base = (size_t)(b*2 + h)*131072
                            + (size_t)(((((kb_*2 + g_)*4 + dt_)*64) + lhi5*16 + llov)*8 + half5*4);
                        *(short4*)&vT_ws[base] = pk;
                    }
                }
            }
        }
    } else if (blk < 1536) {
        // ----- depth_k cast: [b][tt][h][d] fp32 -> k_ws fragment layout -----
        const size_t idx4 = ((size_t)(blk - 512) * 256 + t) * 4;
        const int b  = (int)(idx4 >> 17);
        const int rm = (int)(idx4 & 131071);
        const int tt = rm >> 7, h = (rm >> 6) & 1, d = rm & 63;   // d % 4 == 0
        float4 v = *(const float4*)(dk + idx4);
        short4 pk = make_short4(f2bf(v.x), f2bf(v.y), f2bf(v.z), f2bf(v.w));
        const int kb_ = tt >> 6, nt_ = (tt >> 4) & 3, lloK = tt & 15;
        const int half = d >> 5, lhiK = (d >> 3) & 3, j = d & 7;  // j in {0,4}
        const size_t addr = (size_t)(b*2 + h)*131072
            + (size_t)(((((kb_*4 + nt_)*2 + half)*64) + lhiK*16 + lloK)*8 + j);
        *(short4*)&k_ws[addr] = pk;
    } else {
        // ----- depth_v: direct gather into V fragment layout -----
        const int unit = (blk - 1536)*4 + (t >> 6);   // 0..2047
        const int lane = t & 63, lhi = lane >> 4, llo = lane & 15;
        const int dt_ = unit & 3, g_ = (unit >> 2) & 1;
        const int kb_ = (unit >> 3) & 15, bh = unit >> 7;
        const int b = bh >> 1, h = bh & 1;
        const float* s0 = dv
            + ((size_t)((b*1024 + kb_*64 + g_*32 + lhi*4)*2 + h))*64 + dt_*16 + llo;
        union { short s[8]; sh8 v8; } o;
        #pragma unroll
        for (int jj = 0; jj < 4; ++jj) o.s[jj]     = f2bf(s0[(size_t)jj * 128]);
        #pragma unroll
        for (int jj = 0; jj < 4; ++jj) o.s[4 + jj] = f2bf(s0[(size_t)(16 + jj) * 128]);
        *(sh8*)&vT_ws[((size_t)bh*256 + (kb_*2 + g_)*4 + dt_)*512 + lane*8] = o.v8;
    }
}

// ---------------------------------------------------------------------------
// Attention v8: LDS-pipelined, 32 q/wave (2 subtiles).  3 blocks/CU (grid
// 48x16=768): three independent barrier domains per CU interleave phases, and
// 3 waves/SIMD hide the MFMA->exp2->pack->MFMA dependency chain.  K/V chunks
// DMA'd global->LDS (global_load_lds, 4-deep ring, counted vmcnt(4), raw
// s_barrier).  Pack via single-instr v_cvt_pk_bf16_f32.
// ---------------------------------------------------------------------------
__global__ __launch_bounds__(256) void attn_k(const short* __restrict__ q_ws,
                                              const short* __restrict__ k_ws,
                                              const short* __restrict__ vT_ws,
                                              short* __restrict__ o_ws)
{
    __shared__ alignas(16) short L[4][8][512];   // ring buf: 4 x (4 K + 4 V chunks)
    const int t    = threadIdx.x;
    const int wave = t >> 6, lane = t & 63;
    const int lhi  = lane >> 4, llo = lane & 15;
    const int bh   = blockIdx.y;
    const int b    = bh >> 1, h = bh & 1;
    const int qt   = blockIdx.x;               // 128-q tile index

    const short* qb = q_ws + ((size_t)bh*6144 + qt*128 + wave*32) * 64;
    sh8 qf[2][2];
    #pragma unroll
    for (int s = 0; s < 2; ++s) {
        qf[s][0] = *(const sh8*)(qb + (s*16 + llo)*64 + lhi*8);
        qf[s][1] = *(const sh8*)(qb + (s*16 + llo)*64 + lhi*8 + 32);
    }

    const short* kbase = k_ws  + (size_t)bh*131072;
    const short* vbase = vT_ws + (size_t)bh*131072;

    fx4 zero = {0.f, 0.f, 0.f, 0.f};
    fx4 oacc[2][4];
    fx4 lacc[2];
    #pragma unroll
    for (int s = 0; s < 2; ++s) {
        lacc[s] = zero;
        #pragma unroll
        for (int dt = 0; dt < 4; ++dt) oacc[s][dt] = zero;
    }

    union { unsigned u[4]; sh8 s8; } onesu;
    onesu.u[0] = onesu.u[1] = onesu.u[2] = onesu.u[3] = 0x3F803F80u;  // bf16 1.0 x8
    const sh8 ones = onesu.s8;

    // wave w DMAs K-chunk w and V-chunk w of group g into ring slot g&3.
    auto stage = [&](int g) {
        const short* ks = kbase + ((size_t)g*4 + wave)*512 + lane*8;
        const short* vs = vbase + ((size_t)g*4 + wave)*512 + lane*8;
        GLOAD_LDS16(ks, &L[g & 3][wave][0]);
        GLOAD_LDS16(vs, &L[g & 3][4 + wave][0]);
    };

    stage(0);
    stage(1);                     // outstanding: 4 DMA ops per wave

    for (int g = 0; g < 64; ++g) {
        if (g < 62) {
            stage(g + 2);         // outstanding 6
            asm volatile("s_waitcnt vmcnt(4)" ::: "memory");   // group g landed
        } else if (g == 62) {
            asm volatile("s_waitcnt vmcnt(2)" ::: "memory");
        } else {
            asm volatile("s_waitcnt vmcnt(0)" ::: "memory");
        }
        __builtin_amdgcn_s_barrier();          // all waves' group-g DMAs visible
        __builtin_amdgcn_sched_barrier(0);     // forbid hoisting ds_reads above

        const short* Lb = (const short*)&L[g & 3][0][0];
        const int lo = lane * 8;
        sh8 K0 = *(const sh8*)(Lb + lo);
        sh8 K1 = *(const sh8*)(Lb + 512  + lo);
        sh8 K2 = *(const sh8*)(Lb + 1024 + lo);
        sh8 K3 = *(const sh8*)(Lb + 1536 + lo);
        sh8 V0 = *(const sh8*)(Lb + 2048 + lo);
        sh8 V1 = *(const sh8*)(Lb + 2560 + lo);
        sh8 V2 = *(const sh8*)(Lb + 3072 + lo);
        sh8 V3 = *(const sh8*)(Lb + 3584 + lo);

        #pragma unroll
        for (int s = 0; s < 2; ++s) {
            fx4 stA = MFMA(K0, qf[s][0], zero); stA = MFMA(K1, qf[s][1], stA);
            fx4 stB = MFMA(K2, qf[s][0], zero); stB = MFMA(K3, qf[s][1], stB);
            float pa0 = __builtin_amdgcn_exp2f(stA[0]);
            float pa1 = __builtin_amdgcn_exp2f(stA[1]);
            float pa2 = __builtin_amdgcn_exp2f(stA[2]);
            float pa3 = __builtin_amdgcn_exp2f(stA[3]);
            float pb0 = __builtin_amdgcn_exp2f(stB[0]);
            float pb1 = __builtin_amdgcn_exp2f(stB[1]);
            float pb2 = __builtin_amdgcn_exp2f(stB[2]);
            float pb3 = __builtin_amdgcn_exp2f(stB[3]);
            union { unsigned u[4]; sh8 s8; } pu;
            pu.u[0] = cvtpk(pa0, pa1);
            pu.u[1] = cvtpk(pa2, pa3);
            pu.u[2] = cvtpk(pb0, pb1);
            pu.u[3] = cvtpk(pb2, pb3);
            lacc[s]    = MFMA(pu.s8, ones, lacc[s]);
            oacc[s][0] = MFMA(pu.s8, V0, oacc[s][0]);
            oacc[s][1] = MFMA(pu.s8, V1, oacc[s][1]);
            oacc[s][2] = MFMA(pu.s8, V2, oacc[s][2]);
            oacc[s][3] = MFMA(pu.s8, V3, oacc[s][3]);
        }
    }

    // epilogue: lacc[s][r] already holds the full denominator for q-row
    // s*16 + lhi*4 + r (identical across llo) — no shuffles needed.
    #pragma unroll
    for (int s = 0; s < 2; ++s) {
        #pragma unroll
        for (int r = 0; r < 4; ++r) {
            const float iq = 1.0f / lacc[s][r];
            const int qi = qt*128 + wave*32 + s*16 + lhi*4 + r;
            const int n = qi / 6, g = qi % 6;
            short* orow = o_ws + ((size_t)(b*1024 + n))*768 + g*128 + h*64;
            #pragma unroll
            for (int dt = 0; dt < 4; ++dt)
                orow[dt*16 + llo] = f2bf(oacc[s][dt][r] * iq);
        }
    }
}

// ---------------------------------------------------------------------------
// proj GEMM: out = o(8192x768,bf16) @ Wproj^T + bproj -> fp32.
// 128x64 tiles, grid (12, 64) = 768 blocks = 3/CU balanced (was 384 = 1.5/CU).
// ---------------------------------------------------------------------------
__global__ __launch_bounds__(256) void projgemm_k(const short* __restrict__ o_ws,
                                                  const float* __restrict__ Wp,
                                                  const float* __restrict__ bpj,
                                                  float* __restrict__ out)
{
    __shared__ alignas(16) short Al[128 * 40];
    __shared__ alignas(16) short Bl[64 * 40];
    const int t    = threadIdx.x;
    const int wave = t >> 6, lane = t & 63;
    const int wm   = wave >> 1, wn = wave & 1;
    const int lhi  = lane >> 4, llo = lane & 15;
    const int bm   = blockIdx.y * 128, bn = blockIdx.x * 64;

    const int srow = t >> 1, scol = (t & 1) * 16;       // A stage: 128 rows x 32
    const int brow = t >> 2, bcol = (t & 3) * 8;        // B stage: 64 rows x 32
    const short* ap = o_ws + (size_t)(bm + srow) * 768 + scol;
    const float* bp = Wp   + (size_t)(bn + brow) * 768 + bcol;

    fx4 zero = {0.f, 0.f, 0.f, 0.f};
    fx4 acc[4][2];
    #pragma unroll
    for (int i = 0; i < 4; ++i)
        #pragma unroll
        for (int j = 0; j < 2; ++j) acc[i][j] = zero;

    sh8 qa0 = *(const sh8*)(ap), qa1 = *(const sh8*)(ap + 8);
    float4 pb0 = *(const float4*)(bp), pb1 = *(const float4*)(bp + 4);

    for (int k0 = 0; k0 < 768; k0 += 32) {
        __syncthreads();
        *(sh8*)&Al[srow*40 + scol] = qa0;
        *(sh8*)&Al[srow*40 + scol + 8] = qa1;
        *(sh8*)&Bl[brow*40 + bcol] = pack8(pb0, pb1);
        __syncthreads();
        if (k0 + 32 < 768) {
            qa0 = *(const sh8*)(ap + k0+32);  qa1 = *(const sh8*)(ap + k0+40);
            pb0 = *(const float4*)(bp + k0+32);  pb1 = *(const float4*)(bp + k0+36);
        }
        sh8 af[4], bf[2];
        #pragma unroll
        for (int mt = 0; mt < 4; ++mt)
            af[mt] = *(const sh8*)&Al[(wm*64 + mt*16 + llo)*40 + lhi*8];
        #pragma unroll
        for (int nt = 0; nt < 2; ++nt)
            bf[nt] = *(const sh8*)&Bl[(wn*32 + nt*16 + llo)*40 + lhi*8];
        #pragma unroll
        for (int mt = 0; mt < 4; ++mt)
            #pragma unroll
            for (int nt = 0; nt < 2; ++nt)
                acc[mt][nt] = MFMA(af[mt], bf[nt], acc[mt][nt]);
    }

    #pragma unroll
    for (int nt = 0; nt < 2; ++nt) {
        const int c = bn + wn*32 + nt*16 + llo;
        const float bias = bpj[c];
        #pragma unroll
        for (int mt = 0; mt < 4; ++mt) {
            const int m0 = bm + wm*64 + mt*16 + lhi*4;
            #pragma unroll
            for (int r = 0; r < 4; ++r)
                out[(size_t)(m0 + r)*768 + c] = acc[mt][nt][r] + bias;
        }
    }
}

// ---------------------------------------------------------------------------
extern "C" void kernel_launch(void* const* d_in, const int* in_sizes, int n_in,
                              void* d_out, int out_size, void* d_ws, size_t ws_size,
                              hipStream_t stream)
{
    const float* x   = (const float*)d_in[0];
    const float* dk  = (const float*)d_in[1];
    const float* dv  = (const float*)d_in[2];
    const float* Wq  = (const float*)d_in[3];
    const float* bq  = (const float*)d_in[4];
    const float* Wkv = (const float*)d_in[5];
    const float* bkv = (const float*)d_in[6];
    const float* Wp  = (const float*)d_in[7];
    const float* bpj = (const float*)d_in[8];

    float* out = (float*)d_out;
    float* ok  = out + 6291456;            // k output (8,1024,2,64)
    float* ov  = out + 7340032;            // v output

    char* ws = (char*)d_ws;
    short* q_ws  = (short*)(ws);                    // 12,582,912 B
    short* k_ws  = (short*)(ws + 12582912);         //  4,194,304 B (frag layout)
    short* vT_ws = (short*)(ws + 16777216);         //  4,194,304 B (frag layout)
    short* o_ws  = (short*)(ws + 20971520);         // 12,582,912 B  (32 MiB total)

    prep_k     <<<dim3(2048),   256, 0, stream>>>(x, Wq, bq, Wkv, bkv, dk, dv,
                                                  ok, ov, q_ws, k_ws, vT_ws);
    attn_k     <<<dim3(48, 16), 256, 0, stream>>>(q_ws, k_ws, vT_ws, o_ws);
    projgemm_k <<<dim3(12, 64), 256, 0, stream>>>(o_ws, Wp, bpj, out);
}